// Round 1
// baseline (984.415 us; speedup 1.0000x reference)
//
#include <hip/hip_runtime.h>
#include <hip/hip_bf16.h>
#include <math.h>

#define BB  64
#define CC  64
#define LL  720
#define DD  512
#define PP  336
#define P2C 168
#define HH  512
#define MM  (BB*CC)   // 4096

// ---------------------------------------------------------------------------
// x[b][c][l] = x_bsd[b][l][c]
__global__ __launch_bounds__(256) void k_transpose(const float* __restrict__ xbsd,
                                                   float* __restrict__ x) {
  __shared__ float tile[16][17];
  int b  = blockIdx.z;
  int l0 = blockIdx.x * 16;
  int c0 = blockIdx.y * 16;
  int tx = threadIdx.x, ty = threadIdx.y;
  tile[ty][tx] = xbsd[(size_t)b * LL * CC + (size_t)(l0 + ty) * CC + (c0 + tx)];
  __syncthreads();
  x[(size_t)b * CC * LL + (size_t)(c0 + ty) * LL + (l0 + tx)] = tile[tx][ty];
}

// ---------------------------------------------------------------------------
// h = gelu(A @ W), A: [M=4096][K], W: [K][512], h: [M][512]
__global__ __launch_bounds__(256) void k_gemm_gelu(const float* __restrict__ A,
                                                   const float* __restrict__ W,
                                                   float* __restrict__ O, int K) {
  __shared__ float As[16][68];
  __shared__ float Bs[16][68];
  const int n0 = blockIdx.x * 64;
  const int m0 = blockIdx.y * 64;
  const int tx = threadIdx.x, ty = threadIdx.y;
  const int tid  = ty * 16 + tx;
  const int arow = tid >> 2, aq = (tid & 3) << 2;
  const int brow = tid >> 4, bcol = (tid & 15) << 2;
  float acc[4][4] = {};
  for (int k0 = 0; k0 < K; k0 += 16) {
    float4 av = *(const float4*)(A + (size_t)(m0 + arow) * K + k0 + aq);
    float4 bv = *(const float4*)(W + (size_t)(k0 + brow) * HH + n0 + bcol);
    As[aq + 0][arow] = av.x; As[aq + 1][arow] = av.y;
    As[aq + 2][arow] = av.z; As[aq + 3][arow] = av.w;
    *(float4*)&Bs[brow][bcol] = bv;
    __syncthreads();
#pragma unroll
    for (int kk = 0; kk < 16; ++kk) {
      float4 a4 = *(const float4*)&As[kk][ty << 2];
      float4 b4 = *(const float4*)&Bs[kk][tx << 2];
      float aa[4] = {a4.x, a4.y, a4.z, a4.w};
      float bb[4] = {b4.x, b4.y, b4.z, b4.w};
#pragma unroll
      for (int i = 0; i < 4; ++i)
#pragma unroll
        for (int j = 0; j < 4; ++j) acc[i][j] = fmaf(aa[i], bb[j], acc[i][j]);
    }
    __syncthreads();
  }
#pragma unroll
  for (int i = 0; i < 4; ++i) {
    int m = m0 + (ty << 2) + i;
    float4 o;
    float* po = (float*)&o;
#pragma unroll
    for (int j = 0; j < 4; ++j) {
      float v = acc[i][j];
      po[j] = 0.5f * v * (1.0f + tanhf(0.7978845608028654f * (v + 0.044715f * v * v * v)));
    }
    *(float4*)(O + (size_t)m * HH + n0 + (tx << 2)) = o;
  }
}

// ---------------------------------------------------------------------------
// params = A @ W  (W: [K][2*Nv]); s = exp(tanh(params[:, :Nv])); t = params[:, Nv:]
// Vout = Vin*vscale*s + t
__global__ __launch_bounds__(256) void k_affine(const float* __restrict__ A,
                                                const float* __restrict__ W,
                                                const float* __restrict__ Vin,
                                                float* __restrict__ Vout,
                                                float vscale, int K, int Nv) {
  __shared__ float As[16][68];
  __shared__ float Bs[16][68];
  __shared__ float Bt[16][68];
  const int n0 = blockIdx.x * 64;
  const int m0 = blockIdx.y * 64;
  const int tx = threadIdx.x, ty = threadIdx.y;
  const int tid  = ty * 16 + tx;
  const int arow = tid >> 2, aq = (tid & 3) << 2;
  const int brow = tid >> 4, bcol = (tid & 15) << 2;
  const int ldw = 2 * Nv;
  const bool bok = (n0 + bcol) < Nv;
  float accS[4][4] = {};
  float accT[4][4] = {};
  for (int k0 = 0; k0 < K; k0 += 16) {
    float4 av = *(const float4*)(A + (size_t)(m0 + arow) * K + k0 + aq);
    float4 bs = make_float4(0.f, 0.f, 0.f, 0.f);
    float4 bt = make_float4(0.f, 0.f, 0.f, 0.f);
    if (bok) {
      const float* wr = W + (size_t)(k0 + brow) * ldw + n0 + bcol;
      bs = *(const float4*)(wr);
      bt = *(const float4*)(wr + Nv);
    }
    As[aq + 0][arow] = av.x; As[aq + 1][arow] = av.y;
    As[aq + 2][arow] = av.z; As[aq + 3][arow] = av.w;
    *(float4*)&Bs[brow][bcol] = bs;
    *(float4*)&Bt[brow][bcol] = bt;
    __syncthreads();
#pragma unroll
    for (int kk = 0; kk < 16; ++kk) {
      float4 a4 = *(const float4*)&As[kk][ty << 2];
      float4 b1 = *(const float4*)&Bs[kk][tx << 2];
      float4 b2 = *(const float4*)&Bt[kk][tx << 2];
      float aa[4] = {a4.x, a4.y, a4.z, a4.w};
      float s4[4] = {b1.x, b1.y, b1.z, b1.w};
      float t4[4] = {b2.x, b2.y, b2.z, b2.w};
#pragma unroll
      for (int i = 0; i < 4; ++i) {
#pragma unroll
        for (int j = 0; j < 4; ++j) {
          accS[i][j] = fmaf(aa[i], s4[j], accS[i][j]);
          accT[i][j] = fmaf(aa[i], t4[j], accT[i][j]);
        }
      }
    }
    __syncthreads();
  }
  const int ncol = n0 + (tx << 2);
  if (ncol < Nv) {
#pragma unroll
    for (int i = 0; i < 4; ++i) {
      int m = m0 + (ty << 2) + i;
      float4 v = *(const float4*)(Vin + (size_t)m * Nv + ncol);
      float vv[4] = {v.x, v.y, v.z, v.w};
      float4 o;
      float* po = (float*)&o;
#pragma unroll
      for (int j = 0; j < 4; ++j) {
        float s = expf(tanhf(accS[i][j]));
        po[j] = vv[j] * vscale * s + accT[i][j];
      }
      *(float4*)(Vout + (size_t)m * Nv + ncol) = o;
    }
  }
}

// ---------------------------------------------------------------------------
// Final stage: theta = pi*tanh(Z@W_rot); (scale,shift) = _ss(Z@W_koo);
// out = transpose(rot^-1(koop^-1(koop(rot(y,theta),a,b)*scale, a,b), theta) + shift)
__global__ __launch_bounds__(256) void k_final(const float* __restrict__ Z,
                                               const float* __restrict__ Y,
                                               const float* __restrict__ Wrot,
                                               const float* __restrict__ Wkoo,
                                               const float* __restrict__ Ay,
                                               const float* __restrict__ By,
                                               float* __restrict__ out) {
  __shared__ float As[16][68];
  __shared__ float Wr[16][16];
  __shared__ float Wks[16][34];
  __shared__ float Wkt[16][34];
  const int j0 = blockIdx.x * 16;
  const int m0 = blockIdx.y * 64;
  const int tx = threadIdx.x, ty = threadIdx.y;
  const int tid  = ty * 16 + tx;
  const int arow = tid >> 2, aq = (tid & 3) << 2;
  const int wk = tid >> 4, wj = tid & 15;
  const bool jok = (j0 + wj) < P2C;
  float aTh[4] = {}, aS0[4] = {}, aS1[4] = {}, aT0[4] = {}, aT1[4] = {};
  for (int k0 = 0; k0 < DD; k0 += 16) {
    float4 av = *(const float4*)(Z + (size_t)(m0 + arow) * DD + k0 + aq);
    float  wrv = 0.f;
    float2 wsv = make_float2(0.f, 0.f), wtv = make_float2(0.f, 0.f);
    if (jok) {
      wrv = Wrot[(size_t)(k0 + wk) * P2C + j0 + wj];
      const float* wp = Wkoo + (size_t)(k0 + wk) * (2 * PP) + 2 * (j0 + wj);
      wsv = *(const float2*)(wp);
      wtv = *(const float2*)(wp + PP);
    }
    As[aq + 0][arow] = av.x; As[aq + 1][arow] = av.y;
    As[aq + 2][arow] = av.z; As[aq + 3][arow] = av.w;
    Wr[wk][wj] = wrv;
    *(float2*)&Wks[wk][2 * wj] = wsv;
    *(float2*)&Wkt[wk][2 * wj] = wtv;
    __syncthreads();
#pragma unroll
    for (int kk = 0; kk < 16; ++kk) {
      float4 a4 = *(const float4*)&As[kk][ty << 2];
      float wr  = Wr[kk][tx];
      float2 ws = *(const float2*)&Wks[kk][2 * tx];
      float2 wt = *(const float2*)&Wkt[kk][2 * tx];
      float aa[4] = {a4.x, a4.y, a4.z, a4.w};
#pragma unroll
      for (int i = 0; i < 4; ++i) {
        aTh[i] = fmaf(aa[i], wr,   aTh[i]);
        aS0[i] = fmaf(aa[i], ws.x, aS0[i]);
        aS1[i] = fmaf(aa[i], ws.y, aS1[i]);
        aT0[i] = fmaf(aa[i], wt.x, aT0[i]);
        aT1[i] = fmaf(aa[i], wt.y, aT1[i]);
      }
    }
    __syncthreads();
  }
  const int j = j0 + tx;
  if (j < P2C) {
#pragma unroll
    for (int i = 0; i < 4; ++i) {
      int m = m0 + (ty << 2) + i;
      int b = m >> 6, c = m & 63;
      float2 yv = *(const float2*)(Y + (size_t)m * PP + 2 * j);
      float a  = Ay[c * P2C + j];
      float bb = By[c * P2C + j];
      float rn = rsqrtf(a * a + bb * bb);
      float ca = a * rn, cb = bb * rn;
      float theta = 3.14159265358979323846f * tanhf(aTh[i]);
      float s1v, c1;
      sincosf(theta, &s1v, &c1);
      float sc0 = expf(tanhf(aS0[i]));
      float sc1 = expf(tanhf(aS1[i]));
      float re = yv.x, im = yv.y;
      float r1 = c1 * re - s1v * im,  i1 = s1v * re + c1 * im;   // rot
      float r2 = ca * r1 - cb * i1,   i2 = cb * r1 + ca * i1;    // koop
      float r3 = r2 * sc0,            i3 = i2 * sc1;             // * scale
      float r4 = ca * r3 + cb * i3,   i4 = ca * i3 - cb * r3;    // koop^-1
      float r5 = c1 * r4 + s1v * i4,  i5 = c1 * i4 - s1v * r4;   // rot^-1
      out[(size_t)b * PP * CC + (size_t)(2 * j) * CC + c]     = r5 + aT0[i];
      out[(size_t)b * PP * CC + (size_t)(2 * j + 1) * CC + c] = i5 + aT1[i];
    }
  }
}

// ---------------------------------------------------------------------------
extern "C" void kernel_launch(void* const* d_in, const int* in_sizes, int n_in,
                              void* d_out, int out_size, void* d_ws, size_t ws_size,
                              hipStream_t stream) {
  const float* x_bsd   = (const float*)d_in[0];
  const float* z0      = (const float*)d_in[1];
  const float* y0      = (const float*)d_in[2];
  const float* W_h     = (const float*)d_in[3];
  const float* W_ssz   = (const float*)d_in[4];
  const float* W_xz_v2 = (const float*)d_in[5];
  const float* W_xz_v3 = (const float*)d_in[6];
  const float* W_xz_v4 = (const float*)d_in[7];
  const float* W_xz_v5 = (const float*)d_in[8];
  const float* W_zx_v0 = (const float*)d_in[9];
  const float* W_zx_v2 = (const float*)d_in[10];
  const float* W_zx_v3 = (const float*)d_in[11];
  // d_in[12] = W_zx_v5: x-update after it is never read -> dead, skipped.
  const float* W_zy_v4 = (const float*)d_in[13];
  const float* W_rot   = (const float*)d_in[14];
  const float* W_koo   = (const float*)d_in[15];
  const float* a_y     = (const float*)d_in[16];
  const float* b_y     = (const float*)d_in[17];
  float* out = (float*)d_out;

  float* x = (float*)d_ws;                 // [4096][720]
  float* z = x + (size_t)MM * LL;          // [4096][512]
  float* y = z + (size_t)MM * DD;          // [4096][336]
  float* h = y + (size_t)MM * PP;          // [4096][512]

  dim3 blk(16, 16);

  k_transpose<<<dim3(45, 4, 64), blk, 0, stream>>>(x_bsd, x);
  k_gemm_gelu<<<dim3(8, 64), blk, 0, stream>>>(x, W_h, h, LL);
  // z = affine(z0*0.1, h, W_ssz)
  k_affine<<<dim3(8, 64), blk, 0, stream>>>(h, W_ssz, z0, z, 0.1f, HH, DD);
  // x = affine(x, z, W_zx_v0)
  k_affine<<<dim3(12, 64), blk, 0, stream>>>(z, W_zx_v0, x, x, 1.0f, DD, LL);
  // z = affine(z, x, W_xz_v2)
  k_affine<<<dim3(8, 64), blk, 0, stream>>>(x, W_xz_v2, z, z, 1.0f, LL, DD);
  // x = affine(x, z, W_zx_v2)
  k_affine<<<dim3(12, 64), blk, 0, stream>>>(z, W_zx_v2, x, x, 1.0f, DD, LL);
  // z = affine(z, x, W_xz_v3)
  k_affine<<<dim3(8, 64), blk, 0, stream>>>(x, W_xz_v3, z, z, 1.0f, LL, DD);
  // x = affine(x, z, W_zx_v3)
  k_affine<<<dim3(12, 64), blk, 0, stream>>>(z, W_zx_v3, x, x, 1.0f, DD, LL);
  // z = affine(z, x, W_xz_v4)
  k_affine<<<dim3(8, 64), blk, 0, stream>>>(x, W_xz_v4, z, z, 1.0f, LL, DD);
  // y = affine(y0*0.1, z, W_zy_v4)
  k_affine<<<dim3(6, 64), blk, 0, stream>>>(z, W_zy_v4, y0, y, 0.1f, DD, PP);
  // z = affine(z, x, W_xz_v5)
  k_affine<<<dim3(8, 64), blk, 0, stream>>>(x, W_xz_v5, z, z, 1.0f, LL, DD);
  // (x = affine(x, z, W_zx_v5) skipped: dead)
  k_final<<<dim3(11, 64), blk, 0, stream>>>(z, y, W_rot, W_koo, a_y, b_y, out);
}

// Round 5
// 602.740 us; speedup vs baseline: 1.6332x; 1.6332x over previous
//
#include <hip/hip_runtime.h>
#include <hip/hip_bf16.h>
#include <math.h>

#define BB  64
#define CC  64
#define LL  720
#define LLP 736           // 720 padded to multiple of 32
#define DD  512
#define PP  336
#define P2C 168
#define HH  512
#define MM  (BB*CC)       // 4096

typedef _Float16 f16x8 __attribute__((ext_vector_type(8)));
typedef float    f32x4 __attribute__((ext_vector_type(4)));

// ---------------------------------------------------------------------------
// Batched weight convert: fp32 W[K][N] -> fp16 hi/lo planes Wt[N][Kpad]
// (transposed; hi = f16(w), lo = f16(w - hi); K-pad zeroed)
struct WDesc { const float* src; _Float16* dstHi; _Float16* dstLo;
               int K, N, Kpad, tbase, tilesN; };
struct WTab  { WDesc d[12]; };

__global__ __launch_bounds__(256) void k_convert(WTab tab) {
  __shared__ float tile[16][17];
  const int bid = blockIdx.x;
  int wi = 0;
#pragma unroll
  for (int i = 1; i < 12; ++i) if (bid >= tab.d[i].tbase) wi = i;
  const WDesc d = tab.d[wi];
  const int lt = bid - d.tbase;
  const int tk = lt / d.tilesN, tn = lt % d.tilesN;
  const int k0 = tk * 16, n0 = tn * 16;
  const int tx = threadIdx.x & 15, ty = threadIdx.x >> 4;
  float v = 0.f;
  if (n0 + tx < d.N) v = d.src[(size_t)(k0 + ty) * d.N + n0 + tx];
  tile[ty][tx] = v;
  __syncthreads();
  if (n0 + ty < d.N) {
    const float w = tile[tx][ty];
    const _Float16 h = (_Float16)w;
    const _Float16 l = (_Float16)(w - (float)h);
    const size_t base = (size_t)(n0 + ty) * d.Kpad;
    d.dstHi[base + k0 + tx] = h;
    d.dstLo[base + k0 + tx] = l;
    if (d.Kpad != d.K && k0 + 16 == d.K) {
      d.dstHi[base + d.K + tx] = (_Float16)0.f;
      d.dstLo[base + d.K + tx] = (_Float16)0.f;
    }
  }
}

// ---------------------------------------------------------------------------
// x_bsd [B][L][C] -> x hi/lo [M][736] (pad cols zeroed)
__global__ __launch_bounds__(256) void k_xpose(const float* __restrict__ xbsd,
                                               _Float16* __restrict__ xhi,
                                               _Float16* __restrict__ xlo) {
  __shared__ float tile[16][17];
  const int b = blockIdx.z, l0 = blockIdx.x * 16, c0 = blockIdx.y * 16;
  const int tx = threadIdx.x, ty = threadIdx.y;
  tile[ty][tx] = xbsd[(size_t)b * LL * CC + (size_t)(l0 + ty) * CC + c0 + tx];
  __syncthreads();
  const float v = tile[tx][ty];
  const _Float16 h = (_Float16)v;
  const _Float16 l = (_Float16)(v - (float)h);
  const size_t m = (size_t)b * CC + c0 + ty;
  xhi[m * LLP + l0 + tx] = h;
  xlo[m * LLP + l0 + tx] = l;
  if (l0 == 704) {
    xhi[m * LLP + 720 + tx] = (_Float16)0.f;
    xlo[m * LLP + 720 + tx] = (_Float16)0.f;
  }
}

// ---------------------------------------------------------------------------
// Split-3 MFMA GEMM: BM=128, BN=64, BK=32; 256 threads = 4 waves (32x64/wave).
// A,B given as fp16 hi/lo planes; product = Ahi*Bhi + Ahi*Blo + Alo*Bhi.
// EPI: 0 = affine (dual s/t halves; out = Vin*vscale*exp(tanh(S)) + T)
//      1 = gelu  (single; hi/lo out)
//      2 = raw   (single; transposed fp32 out)
// VIN16: Vin is hi/lo fp16 pair (else fp32). OUT_T: out32[n][M] transposed.
template<int EPI, bool DUAL, bool VIN16, bool OUT_T>
__global__ __launch_bounds__(256)
void k_gemm(const _Float16* __restrict__ Ahi, const _Float16* __restrict__ Alo, int lda,
            const _Float16* __restrict__ Whi, const _Float16* __restrict__ Wlo, int ldw,
            const float* __restrict__ Vin32, const _Float16* __restrict__ VinHi,
            const _Float16* __restrict__ VinLo, int ldv, float vscale,
            float* __restrict__ outT32,
            _Float16* __restrict__ outHi, _Float16* __restrict__ outLo, int ldo,
            int Kp, int Nv) {
  constexpr int NB = DUAL ? 128 : 64;
  __shared__ _Float16 AsHi[128 * 40];
  __shared__ _Float16 AsLo[128 * 40];
  __shared__ _Float16 BsHi[NB * 40];
  __shared__ _Float16 BsLo[NB * 40];
  const int m0 = blockIdx.y * 128;
  const int n0 = blockIdx.x * 64;
  const int tid = threadIdx.x;
  const int w = tid >> 6, lane = tid & 63, q = lane >> 4, r = lane & 15;

  f32x4 accS[2][4] = {};
  f32x4 accT[2][4] = {};

  for (int k0 = 0; k0 < Kp; k0 += 32) {
    // stage A hi/lo: 128 rows x 32 halves each
#pragma unroll
    for (int p = 0; p < 2; ++p) {
      const int idx = p * 256 + tid;
      const int row = idx >> 2, seg = idx & 3;
      const size_t off = (size_t)(m0 + row) * lda + k0 + seg * 8;
      *(f16x8*)(&AsHi[row * 40 + seg * 8]) = *(const f16x8*)(Ahi + off);
      *(f16x8*)(&AsLo[row * 40 + seg * 8]) = *(const f16x8*)(Alo + off);
    }
    // stage B hi/lo
#pragma unroll
    for (int p = 0; p < NB / 64; ++p) {
      const int idx = p * 256 + tid;
      const int row = idx >> 2, seg = idx & 3;
      const int nr  = row & 63;
      const int wrow = (row < 64) ? (n0 + nr) : (Nv + n0 + nr);
      f16x8 vh = {0, 0, 0, 0, 0, 0, 0, 0};
      f16x8 vl = {0, 0, 0, 0, 0, 0, 0, 0};
      if (n0 + nr < Nv) {
        const size_t off = (size_t)wrow * ldw + k0 + seg * 8;
        vh = *(const f16x8*)(Whi + off);
        vl = *(const f16x8*)(Wlo + off);
      }
      *(f16x8*)(&BsHi[row * 40 + seg * 8]) = vh;
      *(f16x8*)(&BsLo[row * 40 + seg * 8]) = vl;
    }
    __syncthreads();
    f16x8 afh[2], afl[2];
#pragma unroll
    for (int i = 0; i < 2; ++i) {
      afh[i] = *(const f16x8*)(&AsHi[(w * 32 + i * 16 + r) * 40 + q * 8]);
      afl[i] = *(const f16x8*)(&AsLo[(w * 32 + i * 16 + r) * 40 + q * 8]);
    }
#pragma unroll
    for (int j = 0; j < 4; ++j) {
      const f16x8 bh = *(const f16x8*)(&BsHi[(j * 16 + r) * 40 + q * 8]);
      const f16x8 bl = *(const f16x8*)(&BsLo[(j * 16 + r) * 40 + q * 8]);
#pragma unroll
      for (int i = 0; i < 2; ++i) {
        accS[i][j] = __builtin_amdgcn_mfma_f32_16x16x32_f16(afh[i], bh, accS[i][j], 0, 0, 0);
        accS[i][j] = __builtin_amdgcn_mfma_f32_16x16x32_f16(afl[i], bh, accS[i][j], 0, 0, 0);
        accS[i][j] = __builtin_amdgcn_mfma_f32_16x16x32_f16(afh[i], bl, accS[i][j], 0, 0, 0);
      }
      if (DUAL) {
        const f16x8 ch = *(const f16x8*)(&BsHi[(64 + j * 16 + r) * 40 + q * 8]);
        const f16x8 cl = *(const f16x8*)(&BsLo[(64 + j * 16 + r) * 40 + q * 8]);
#pragma unroll
        for (int i = 0; i < 2; ++i) {
          accT[i][j] = __builtin_amdgcn_mfma_f32_16x16x32_f16(afh[i], ch, accT[i][j], 0, 0, 0);
          accT[i][j] = __builtin_amdgcn_mfma_f32_16x16x32_f16(afl[i], ch, accT[i][j], 0, 0, 0);
          accT[i][j] = __builtin_amdgcn_mfma_f32_16x16x32_f16(afh[i], cl, accT[i][j], 0, 0, 0);
        }
      }
    }
    __syncthreads();
  }

  // epilogue: m = m0 + w*32 + i*16 + q*4 + g,  n = n0 + j*16 + r
  const int mb = m0 + w * 32 + q * 4;
#pragma unroll
  for (int i = 0; i < 2; ++i) {
#pragma unroll
    for (int j = 0; j < 4; ++j) {
      const int n = n0 + j * 16 + r;
      if (n >= Nv) continue;
      if (EPI == 2) {
        *(f32x4*)(outT32 + (size_t)n * MM + mb + i * 16) = accS[i][j];
      } else if (EPI == 1) {
#pragma unroll
        for (int g = 0; g < 4; ++g) {
          const int m = mb + i * 16 + g;
          const float v = accS[i][j][g];
          const float o = 0.5f * v * (1.0f + tanhf(0.7978845608028654f * (v + 0.044715f * v * v * v)));
          const _Float16 h = (_Float16)o;
          outHi[(size_t)m * ldo + n] = h;
          outLo[(size_t)m * ldo + n] = (_Float16)(o - (float)h);
        }
      } else {
        f32x4 o;
#pragma unroll
        for (int g = 0; g < 4; ++g) {
          const int m = mb + i * 16 + g;
          float v;
          if (VIN16) {
            v = (float)VinHi[(size_t)m * ldv + n] + (float)VinLo[(size_t)m * ldv + n];
          } else {
            v = Vin32[(size_t)m * ldv + n];
          }
          const float s = expf(tanhf(accS[i][j][g]));
          o[g] = v * vscale * s + accT[i][j][g];
        }
        if (OUT_T) {
          *(f32x4*)(outT32 + (size_t)n * MM + mb + i * 16) = o;
        } else {
#pragma unroll
          for (int g = 0; g < 4; ++g) {
            const int m = mb + i * 16 + g;
            const _Float16 h = (_Float16)o[g];
            outHi[(size_t)m * ldo + n] = h;
            outLo[(size_t)m * ldo + n] = (_Float16)(o[g] - (float)h);
          }
        }
      }
    }
  }
}

// ---------------------------------------------------------------------------
// Final elementwise: Pt[840][M] (theta raw | S raw | T), yT[336][M] -> out[B][336][C]
__global__ __launch_bounds__(256) void k_final(const float* __restrict__ Pt,
                                               const float* __restrict__ yT,
                                               const float* __restrict__ Ay,
                                               const float* __restrict__ By,
                                               float* __restrict__ out) {
  const int c = threadIdx.x;                       // 0..63
  const int j = blockIdx.x * 4 + threadIdx.y;      // 0..167
  const int b = blockIdx.y;
  const int m = b * 64 + c;
  const float th = 3.14159265358979323846f * tanhf(Pt[(size_t)j * MM + m]);
  const float sc0 = expf(tanhf(Pt[(size_t)(168 + 2 * j) * MM + m]));
  const float sc1 = expf(tanhf(Pt[(size_t)(169 + 2 * j) * MM + m]));
  const float t0 = Pt[(size_t)(504 + 2 * j) * MM + m];
  const float t1 = Pt[(size_t)(505 + 2 * j) * MM + m];
  const float re = yT[(size_t)(2 * j) * MM + m];
  const float im = yT[(size_t)(2 * j + 1) * MM + m];
  const float a = Ay[c * P2C + j], bb = By[c * P2C + j];
  const float rn = rsqrtf(a * a + bb * bb);
  const float ca = a * rn, cb = bb * rn;
  float s1v, c1;
  sincosf(th, &s1v, &c1);
  const float r1 = c1 * re - s1v * im, i1 = s1v * re + c1 * im;   // rot
  const float r2 = ca * r1 - cb * i1,  i2 = cb * r1 + ca * i1;    // koop
  const float r3 = r2 * sc0,           i3 = i2 * sc1;             // * scale
  const float r4 = ca * r3 + cb * i3,  i4 = ca * i3 - cb * r3;    // koop^-1
  const float r5 = c1 * r4 + s1v * i4, i5 = c1 * i4 - s1v * r4;   // rot^-1
  out[(size_t)b * PP * CC + (size_t)(2 * j) * CC + c]     = r5 + t0;
  out[(size_t)b * PP * CC + (size_t)(2 * j + 1) * CC + c] = i5 + t1;
}

// ---------------------------------------------------------------------------
extern "C" void kernel_launch(void* const* d_in, const int* in_sizes, int n_in,
                              void* d_out, int out_size, void* d_ws, size_t ws_size,
                              hipStream_t stream) {
  const float* x_bsd   = (const float*)d_in[0];
  const float* z0      = (const float*)d_in[1];
  const float* y0      = (const float*)d_in[2];
  const float* W_h     = (const float*)d_in[3];
  const float* W_ssz   = (const float*)d_in[4];
  const float* W_xz_v2 = (const float*)d_in[5];
  const float* W_xz_v3 = (const float*)d_in[6];
  const float* W_xz_v4 = (const float*)d_in[7];
  const float* W_xz_v5 = (const float*)d_in[8];
  const float* W_zx_v0 = (const float*)d_in[9];
  const float* W_zx_v2 = (const float*)d_in[10];
  const float* W_zx_v3 = (const float*)d_in[11];
  // d_in[12] = W_zx_v5: dead (x never read after), skipped
  const float* W_zy_v4 = (const float*)d_in[13];
  const float* W_rot   = (const float*)d_in[14];
  const float* W_koo   = (const float*)d_in[15];
  const float* a_y     = (const float*)d_in[16];
  const float* b_y     = (const float*)d_in[17];
  float* out = (float*)d_out;

  char* p = (char*)d_ws;
  auto alloc = [&](size_t bytes) -> void* {
    void* r = (void*)p; p += (bytes + 255) & ~(size_t)255; return r;
  };
  float*    yT  = (float*)alloc((size_t)PP * MM * 4);
  float*    Pt  = (float*)alloc((size_t)(P2C * 5) * MM * 4);  // 840 rows
  _Float16* xhi = (_Float16*)alloc((size_t)MM * LLP * 2);
  _Float16* xlo = (_Float16*)alloc((size_t)MM * LLP * 2);
  _Float16* zhi = (_Float16*)alloc((size_t)MM * DD * 2);
  _Float16* zlo = (_Float16*)alloc((size_t)MM * DD * 2);
  _Float16* hhi = (_Float16*)alloc((size_t)MM * HH * 2);
  _Float16* hlo = (_Float16*)alloc((size_t)MM * HH * 2);
  auto wpair = [&](size_t elems, _Float16** lo) -> _Float16* {
    _Float16* hi = (_Float16*)alloc(elems * 2);
    *lo = (_Float16*)alloc(elems * 2);
    return hi;
  };
  _Float16 *tWhL, *tWsszL, *tWxz2L, *tWxz3L, *tWxz4L, *tWxz5L;
  _Float16 *tWzx0L, *tWzx2L, *tWzx3L, *tWzyL, *tWcatL;
  _Float16* tWh   = wpair((size_t)HH * LLP, &tWhL);
  _Float16* tWssz = wpair((size_t)(2*DD) * DD, &tWsszL);
  _Float16* tWxz2 = wpair((size_t)(2*DD) * LLP, &tWxz2L);
  _Float16* tWxz3 = wpair((size_t)(2*DD) * LLP, &tWxz3L);
  _Float16* tWxz4 = wpair((size_t)(2*DD) * LLP, &tWxz4L);
  _Float16* tWxz5 = wpair((size_t)(2*DD) * LLP, &tWxz5L);
  _Float16* tWzx0 = wpair((size_t)(2*LL) * DD, &tWzx0L);
  _Float16* tWzx2 = wpair((size_t)(2*LL) * DD, &tWzx2L);
  _Float16* tWzx3 = wpair((size_t)(2*LL) * DD, &tWzx3L);
  _Float16* tWzy  = wpair((size_t)(2*PP) * DD, &tWzyL);
  _Float16* tWcat = wpair((size_t)(P2C*5) * DD, &tWcatL);   // [840][512]

  // ---- weight convert table
  WTab tab;
  int base = 0;
  auto put = [&](int i, const float* src, _Float16* dh, _Float16* dl,
                 int K, int N, int Kpad) {
    const int tN = (N + 15) / 16;
    tab.d[i] = WDesc{src, dh, dl, K, N, Kpad, base, tN};
    base += ((K + 15) / 16) * tN;
  };
  put(0,  W_h,     tWh,   tWhL,   LL, HH,   LLP);
  put(1,  W_ssz,   tWssz, tWsszL, DD, 2*DD, DD);
  put(2,  W_xz_v2, tWxz2, tWxz2L, LL, 2*DD, LLP);
  put(3,  W_xz_v3, tWxz3, tWxz3L, LL, 2*DD, LLP);
  put(4,  W_xz_v4, tWxz4, tWxz4L, LL, 2*DD, LLP);
  put(5,  W_xz_v5, tWxz5, tWxz5L, LL, 2*DD, LLP);
  put(6,  W_zx_v0, tWzx0, tWzx0L, DD, 2*LL, DD);
  put(7,  W_zx_v2, tWzx2, tWzx2L, DD, 2*LL, DD);
  put(8,  W_zx_v3, tWzx3, tWzx3L, DD, 2*LL, DD);
  put(9,  W_zy_v4, tWzy,  tWzyL,  DD, 2*PP, DD);
  put(10, W_rot,   tWcat, tWcatL, DD, P2C,  DD);
  put(11, W_koo,   tWcat + (size_t)P2C * DD, tWcatL + (size_t)P2C * DD, DD, 2*PP, DD);
  const int total_tiles = base;

  k_convert<<<dim3(total_tiles), dim3(256), 0, stream>>>(tab);
  k_xpose<<<dim3(45, 4, 64), dim3(16, 16), 0, stream>>>(x_bsd, xhi, xlo);

  const dim3 blk(256);
  // h = gelu(x @ W_h)
  k_gemm<1, false, false, false><<<dim3(8, 32), blk, 0, stream>>>(
      xhi, xlo, LLP, tWh, tWhL, LLP,
      nullptr, nullptr, nullptr, 0, 0.f, nullptr, hhi, hlo, HH, LLP, HH);
  // z = affine(z0*0.1, h, W_ssz)
  k_gemm<0, true, false, false><<<dim3(8, 32), blk, 0, stream>>>(
      hhi, hlo, HH, tWssz, tWsszL, DD,
      z0, nullptr, nullptr, DD, 0.1f, nullptr, zhi, zlo, DD, DD, DD);
  // x = affine(x, z, W_zx_v0)
  k_gemm<0, true, true, false><<<dim3(12, 32), blk, 0, stream>>>(
      zhi, zlo, DD, tWzx0, tWzx0L, DD,
      nullptr, xhi, xlo, LLP, 1.f, nullptr, xhi, xlo, LLP, DD, LL);
  // z = affine(z, x, W_xz_v2)
  k_gemm<0, true, true, false><<<dim3(8, 32), blk, 0, stream>>>(
      xhi, xlo, LLP, tWxz2, tWxz2L, LLP,
      nullptr, zhi, zlo, DD, 1.f, nullptr, zhi, zlo, DD, LLP, DD);
  // x = affine(x, z, W_zx_v2)
  k_gemm<0, true, true, false><<<dim3(12, 32), blk, 0, stream>>>(
      zhi, zlo, DD, tWzx2, tWzx2L, DD,
      nullptr, xhi, xlo, LLP, 1.f, nullptr, xhi, xlo, LLP, DD, LL);
  // z = affine(z, x, W_xz_v3)
  k_gemm<0, true, true, false><<<dim3(8, 32), blk, 0, stream>>>(
      xhi, xlo, LLP, tWxz3, tWxz3L, LLP,
      nullptr, zhi, zlo, DD, 1.f, nullptr, zhi, zlo, DD, LLP, DD);
  // x = affine(x, z, W_zx_v3)
  k_gemm<0, true, true, false><<<dim3(12, 32), blk, 0, stream>>>(
      zhi, zlo, DD, tWzx3, tWzx3L, DD,
      nullptr, xhi, xlo, LLP, 1.f, nullptr, xhi, xlo, LLP, DD, LL);
  // z = affine(z, x, W_xz_v4)
  k_gemm<0, true, true, false><<<dim3(8, 32), blk, 0, stream>>>(
      xhi, xlo, LLP, tWxz4, tWxz4L, LLP,
      nullptr, zhi, zlo, DD, 1.f, nullptr, zhi, zlo, DD, LLP, DD);
  // yT = affine(y0*0.1, z, W_zy_v4)  [transposed fp32 out]
  k_gemm<0, true, false, true><<<dim3(6, 32), blk, 0, stream>>>(
      zhi, zlo, DD, tWzy, tWzyL, DD,
      y0, nullptr, nullptr, PP, 0.1f, yT, nullptr, nullptr, 0, DD, PP);
  // z = affine(z, x, W_xz_v5)
  k_gemm<0, true, true, false><<<dim3(8, 32), blk, 0, stream>>>(
      xhi, xlo, LLP, tWxz5, tWxz5L, LLP,
      nullptr, zhi, zlo, DD, 1.f, nullptr, zhi, zlo, DD, LLP, DD);
  // Pt = z @ [W_rot | W_koo]  (raw, transposed fp32 out): 840 cols
  k_gemm<2, false, false, true><<<dim3(14, 32), blk, 0, stream>>>(
      zhi, zlo, DD, tWcat, tWcatL, DD,
      nullptr, nullptr, nullptr, 0, 0.f, Pt, nullptr, nullptr, 0, DD, P2C * 5);
  // final elementwise + transposed store
  k_final<<<dim3(42, 64), dim3(64, 4), 0, stream>>>(Pt, yT, a_y, b_y, out);
}

// Round 6
// 540.235 us; speedup vs baseline: 1.8222x; 1.1157x over previous
//
#include <hip/hip_runtime.h>
#include <hip/hip_bf16.h>
#include <math.h>

#define BB  64
#define CC  64
#define LL  720
#define LLP 736           // 720 padded to multiple of 32
#define DD  512
#define PP  336
#define P2C 168
#define HH  512
#define MM  (BB*CC)       // 4096

typedef _Float16 f16x8 __attribute__((ext_vector_type(8)));
typedef float    f32x4 __attribute__((ext_vector_type(4)));

// ---------------------------------------------------------------------------
// Batched weight convert: fp32 W[K][N] -> fp16 hi/lo planes Wt[N][Kpad]
// (transposed; hi = f16(w), lo = f16(w - hi); K-pad zeroed)
struct WDesc { const float* src; _Float16* dstHi; _Float16* dstLo;
               int K, N, Kpad, tbase, tilesN; };
struct WTab  { WDesc d[12]; };

__global__ __launch_bounds__(256) void k_convert(WTab tab) {
  __shared__ float tile[16][17];
  const int bid = blockIdx.x;
  int wi = 0;
#pragma unroll
  for (int i = 1; i < 12; ++i) if (bid >= tab.d[i].tbase) wi = i;
  const WDesc d = tab.d[wi];
  const int lt = bid - d.tbase;
  const int tk = lt / d.tilesN, tn = lt % d.tilesN;
  const int k0 = tk * 16, n0 = tn * 16;
  const int tx = threadIdx.x & 15, ty = threadIdx.x >> 4;
  float v = 0.f;
  if (n0 + tx < d.N) v = d.src[(size_t)(k0 + ty) * d.N + n0 + tx];
  tile[ty][tx] = v;
  __syncthreads();
  if (n0 + ty < d.N) {
    const float w = tile[tx][ty];
    const _Float16 h = (_Float16)w;
    const _Float16 l = (_Float16)(w - (float)h);
    const size_t base = (size_t)(n0 + ty) * d.Kpad;
    d.dstHi[base + k0 + tx] = h;
    d.dstLo[base + k0 + tx] = l;
    if (d.Kpad != d.K && k0 + 16 == d.K) {
      d.dstHi[base + d.K + tx] = (_Float16)0.f;
      d.dstLo[base + d.K + tx] = (_Float16)0.f;
    }
  }
}

// ---------------------------------------------------------------------------
// x_bsd [B][L][C] -> x hi/lo [M][736] (pad cols zeroed)
__global__ __launch_bounds__(256) void k_xpose(const float* __restrict__ xbsd,
                                               _Float16* __restrict__ xhi,
                                               _Float16* __restrict__ xlo) {
  __shared__ float tile[16][17];
  const int b = blockIdx.z, l0 = blockIdx.x * 16, c0 = blockIdx.y * 16;
  const int tx = threadIdx.x, ty = threadIdx.y;
  tile[ty][tx] = xbsd[(size_t)b * LL * CC + (size_t)(l0 + ty) * CC + c0 + tx];
  __syncthreads();
  const float v = tile[tx][ty];
  const _Float16 h = (_Float16)v;
  const _Float16 l = (_Float16)(v - (float)h);
  const size_t m = (size_t)b * CC + c0 + ty;
  xhi[m * LLP + l0 + tx] = h;
  xlo[m * LLP + l0 + tx] = l;
  if (l0 == 704) {
    xhi[m * LLP + 720 + tx] = (_Float16)0.f;
    xlo[m * LLP + 720 + tx] = (_Float16)0.f;
  }
}

// ---------------------------------------------------------------------------
// Split-3 MFMA GEMM: BM=64, BN=64, BK=32; 256 threads = 4 waves.
// Wave w owns rows [w*16, w*16+16) x all 64 (or 128 dual) staged cols.
// A,B given as fp16 hi/lo planes; product = Ahi*Bhi + Ahi*Blo + Alo*Bhi.
// EPI: 0 = affine (dual s/t halves; out = Vin*vscale*exp(tanh(S)) + T)
//      1 = gelu  (single; hi/lo out)
//      2 = raw   (single; transposed fp32 out)
// VIN16: Vin is hi/lo fp16 pair (else fp32). OUT_T: out32[n][M] transposed.
template<int EPI, bool DUAL, bool VIN16, bool OUT_T>
__global__ __launch_bounds__(256, 4)
void k_gemm(const _Float16* __restrict__ Ahi, const _Float16* __restrict__ Alo, int lda,
            const _Float16* __restrict__ Whi, const _Float16* __restrict__ Wlo, int ldw,
            const float* __restrict__ Vin32, const _Float16* __restrict__ VinHi,
            const _Float16* __restrict__ VinLo, int ldv, float vscale,
            float* __restrict__ outT32,
            _Float16* __restrict__ outHi, _Float16* __restrict__ outLo, int ldo,
            int Kp, int Nv) {
  constexpr int NB = DUAL ? 128 : 64;
  __shared__ _Float16 AsHi[64 * 40];
  __shared__ _Float16 AsLo[64 * 40];
  __shared__ _Float16 BsHi[NB * 40];
  __shared__ _Float16 BsLo[NB * 40];
  const int m0 = blockIdx.y * 64;
  const int n0 = blockIdx.x * 64;
  const int tid = threadIdx.x;
  const int w = tid >> 6, lane = tid & 63, q = lane >> 4, r = lane & 15;

  f32x4 accS[4] = {};
  f32x4 accT[4] = {};

  const int arow = tid >> 2, aseg = tid & 3;        // A-stage: 64 rows x 4 segs

  for (int k0 = 0; k0 < Kp; k0 += 32) {
    // stage A hi/lo: 64 rows x 32 halves (one round)
    {
      const size_t off = (size_t)(m0 + arow) * lda + k0 + aseg * 8;
      *(f16x8*)(&AsHi[arow * 40 + aseg * 8]) = *(const f16x8*)(Ahi + off);
      *(f16x8*)(&AsLo[arow * 40 + aseg * 8]) = *(const f16x8*)(Alo + off);
    }
    // stage B hi/lo: NB rows x 32 halves
#pragma unroll
    for (int p = 0; p < NB / 64; ++p) {
      const int idx = p * 256 + tid;
      const int row = idx >> 2, seg = idx & 3;
      const int nr  = row & 63;
      const int wrow = (row < 64) ? (n0 + nr) : (Nv + n0 + nr);
      f16x8 vh = {0, 0, 0, 0, 0, 0, 0, 0};
      f16x8 vl = {0, 0, 0, 0, 0, 0, 0, 0};
      if (n0 + nr < Nv) {
        const size_t off = (size_t)wrow * ldw + k0 + seg * 8;
        vh = *(const f16x8*)(Whi + off);
        vl = *(const f16x8*)(Wlo + off);
      }
      *(f16x8*)(&BsHi[row * 40 + seg * 8]) = vh;
      *(f16x8*)(&BsLo[row * 40 + seg * 8]) = vl;
    }
    __syncthreads();
    const f16x8 ah = *(const f16x8*)(&AsHi[(w * 16 + r) * 40 + q * 8]);
    const f16x8 al = *(const f16x8*)(&AsLo[(w * 16 + r) * 40 + q * 8]);
#pragma unroll
    for (int j = 0; j < 4; ++j) {
      const f16x8 bh = *(const f16x8*)(&BsHi[(j * 16 + r) * 40 + q * 8]);
      const f16x8 bl = *(const f16x8*)(&BsLo[(j * 16 + r) * 40 + q * 8]);
      accS[j] = __builtin_amdgcn_mfma_f32_16x16x32_f16(ah, bh, accS[j], 0, 0, 0);
      accS[j] = __builtin_amdgcn_mfma_f32_16x16x32_f16(al, bh, accS[j], 0, 0, 0);
      accS[j] = __builtin_amdgcn_mfma_f32_16x16x32_f16(ah, bl, accS[j], 0, 0, 0);
      if (DUAL) {
        const f16x8 ch = *(const f16x8*)(&BsHi[(64 + j * 16 + r) * 40 + q * 8]);
        const f16x8 cl = *(const f16x8*)(&BsLo[(64 + j * 16 + r) * 40 + q * 8]);
        accT[j] = __builtin_amdgcn_mfma_f32_16x16x32_f16(ah, ch, accT[j], 0, 0, 0);
        accT[j] = __builtin_amdgcn_mfma_f32_16x16x32_f16(al, ch, accT[j], 0, 0, 0);
        accT[j] = __builtin_amdgcn_mfma_f32_16x16x32_f16(ah, cl, accT[j], 0, 0, 0);
      }
    }
    __syncthreads();
  }

  // epilogue: m = m0 + w*16 + q*4 + g,  n = n0 + j*16 + r
  const int mb = m0 + w * 16 + q * 4;
#pragma unroll
  for (int j = 0; j < 4; ++j) {
    const int n = n0 + j * 16 + r;
    if (n >= Nv) continue;
    if (EPI == 2) {
      *(f32x4*)(outT32 + (size_t)n * MM + mb) = accS[j];
    } else if (EPI == 1) {
#pragma unroll
      for (int g = 0; g < 4; ++g) {
        const int m = mb + g;
        const float v = accS[j][g];
        const float o = 0.5f * v * (1.0f + tanhf(0.7978845608028654f * (v + 0.044715f * v * v * v)));
        const _Float16 h = (_Float16)o;
        outHi[(size_t)m * ldo + n] = h;
        outLo[(size_t)m * ldo + n] = (_Float16)(o - (float)h);
      }
    } else {
      f32x4 o;
#pragma unroll
      for (int g = 0; g < 4; ++g) {
        const int m = mb + g;
        float v;
        if (VIN16) {
          v = (float)VinHi[(size_t)m * ldv + n] + (float)VinLo[(size_t)m * ldv + n];
        } else {
          v = Vin32[(size_t)m * ldv + n];
        }
        const float s = expf(tanhf(accS[j][g]));
        o[g] = v * vscale * s + accT[j][g];
      }
      if (OUT_T) {
        *(f32x4*)(outT32 + (size_t)n * MM + mb) = o;
      } else {
#pragma unroll
        for (int g = 0; g < 4; ++g) {
          const int m = mb + g;
          const _Float16 h = (_Float16)o[g];
          outHi[(size_t)m * ldo + n] = h;
          outLo[(size_t)m * ldo + n] = (_Float16)(o[g] - (float)h);
        }
      }
    }
  }
}

// ---------------------------------------------------------------------------
// Final elementwise: Pt[840][M] (theta raw | S raw | T), yT[336][M] -> out[B][336][C]
__global__ __launch_bounds__(256) void k_final(const float* __restrict__ Pt,
                                               const float* __restrict__ yT,
                                               const float* __restrict__ Ay,
                                               const float* __restrict__ By,
                                               float* __restrict__ out) {
  const int c = threadIdx.x;                       // 0..63
  const int j = blockIdx.x * 4 + threadIdx.y;      // 0..167
  const int b = blockIdx.y;
  const int m = b * 64 + c;
  const float th = 3.14159265358979323846f * tanhf(Pt[(size_t)j * MM + m]);
  const float sc0 = expf(tanhf(Pt[(size_t)(168 + 2 * j) * MM + m]));
  const float sc1 = expf(tanhf(Pt[(size_t)(169 + 2 * j) * MM + m]));
  const float t0 = Pt[(size_t)(504 + 2 * j) * MM + m];
  const float t1 = Pt[(size_t)(505 + 2 * j) * MM + m];
  const float re = yT[(size_t)(2 * j) * MM + m];
  const float im = yT[(size_t)(2 * j + 1) * MM + m];
  const float a = Ay[c * P2C + j], bb = By[c * P2C + j];
  const float rn = rsqrtf(a * a + bb * bb);
  const float ca = a * rn, cb = bb * rn;
  float s1v, c1;
  sincosf(th, &s1v, &c1);
  const float r1 = c1 * re - s1v * im, i1 = s1v * re + c1 * im;   // rot
  const float r2 = ca * r1 - cb * i1,  i2 = cb * r1 + ca * i1;    // koop
  const float r3 = r2 * sc0,           i3 = i2 * sc1;             // * scale
  const float r4 = ca * r3 + cb * i3,  i4 = ca * i3 - cb * r3;    // koop^-1
  const float r5 = c1 * r4 + s1v * i4, i5 = c1 * i4 - s1v * r4;   // rot^-1
  out[(size_t)b * PP * CC + (size_t)(2 * j) * CC + c]     = r5 + t0;
  out[(size_t)b * PP * CC + (size_t)(2 * j + 1) * CC + c] = i5 + t1;
}

// ---------------------------------------------------------------------------
extern "C" void kernel_launch(void* const* d_in, const int* in_sizes, int n_in,
                              void* d_out, int out_size, void* d_ws, size_t ws_size,
                              hipStream_t stream) {
  const float* x_bsd   = (const float*)d_in[0];
  const float* z0      = (const float*)d_in[1];
  const float* y0      = (const float*)d_in[2];
  const float* W_h     = (const float*)d_in[3];
  const float* W_ssz   = (const float*)d_in[4];
  const float* W_xz_v2 = (const float*)d_in[5];
  const float* W_xz_v3 = (const float*)d_in[6];
  const float* W_xz_v4 = (const float*)d_in[7];
  const float* W_xz_v5 = (const float*)d_in[8];
  const float* W_zx_v0 = (const float*)d_in[9];
  const float* W_zx_v2 = (const float*)d_in[10];
  const float* W_zx_v3 = (const float*)d_in[11];
  // d_in[12] = W_zx_v5: dead (x never read after), skipped
  const float* W_zy_v4 = (const float*)d_in[13];
  const float* W_rot   = (const float*)d_in[14];
  const float* W_koo   = (const float*)d_in[15];
  const float* a_y     = (const float*)d_in[16];
  const float* b_y     = (const float*)d_in[17];
  float* out = (float*)d_out;

  char* p = (char*)d_ws;
  auto alloc = [&](size_t bytes) -> void* {
    void* r = (void*)p; p += (bytes + 255) & ~(size_t)255; return r;
  };
  float*    yT  = (float*)alloc((size_t)PP * MM * 4);
  float*    Pt  = (float*)alloc((size_t)(P2C * 5) * MM * 4);  // 840 rows
  _Float16* xhi = (_Float16*)alloc((size_t)MM * LLP * 2);
  _Float16* xlo = (_Float16*)alloc((size_t)MM * LLP * 2);
  _Float16* zhi = (_Float16*)alloc((size_t)MM * DD * 2);
  _Float16* zlo = (_Float16*)alloc((size_t)MM * DD * 2);
  _Float16* hhi = (_Float16*)alloc((size_t)MM * HH * 2);
  _Float16* hlo = (_Float16*)alloc((size_t)MM * HH * 2);
  auto wpair = [&](size_t elems, _Float16** lo) -> _Float16* {
    _Float16* hi = (_Float16*)alloc(elems * 2);
    *lo = (_Float16*)alloc(elems * 2);
    return hi;
  };
  _Float16 *tWhL, *tWsszL, *tWxz2L, *tWxz3L, *tWxz4L, *tWxz5L;
  _Float16 *tWzx0L, *tWzx2L, *tWzx3L, *tWzyL, *tWcatL;
  _Float16* tWh   = wpair((size_t)HH * LLP, &tWhL);
  _Float16* tWssz = wpair((size_t)(2*DD) * DD, &tWsszL);
  _Float16* tWxz2 = wpair((size_t)(2*DD) * LLP, &tWxz2L);
  _Float16* tWxz3 = wpair((size_t)(2*DD) * LLP, &tWxz3L);
  _Float16* tWxz4 = wpair((size_t)(2*DD) * LLP, &tWxz4L);
  _Float16* tWxz5 = wpair((size_t)(2*DD) * LLP, &tWxz5L);
  _Float16* tWzx0 = wpair((size_t)(2*LL) * DD, &tWzx0L);
  _Float16* tWzx2 = wpair((size_t)(2*LL) * DD, &tWzx2L);
  _Float16* tWzx3 = wpair((size_t)(2*LL) * DD, &tWzx3L);
  _Float16* tWzy  = wpair((size_t)(2*PP) * DD, &tWzyL);
  _Float16* tWcat = wpair((size_t)(P2C*5) * DD, &tWcatL);   // [840][512]

  // ---- weight convert table
  WTab tab;
  int base = 0;
  auto put = [&](int i, const float* src, _Float16* dh, _Float16* dl,
                 int K, int N, int Kpad) {
    const int tN = (N + 15) / 16;
    tab.d[i] = WDesc{src, dh, dl, K, N, Kpad, base, tN};
    base += ((K + 15) / 16) * tN;
  };
  put(0,  W_h,     tWh,   tWhL,   LL, HH,   LLP);
  put(1,  W_ssz,   tWssz, tWsszL, DD, 2*DD, DD);
  put(2,  W_xz_v2, tWxz2, tWxz2L, LL, 2*DD, LLP);
  put(3,  W_xz_v3, tWxz3, tWxz3L, LL, 2*DD, LLP);
  put(4,  W_xz_v4, tWxz4, tWxz4L, LL, 2*DD, LLP);
  put(5,  W_xz_v5, tWxz5, tWxz5L, LL, 2*DD, LLP);
  put(6,  W_zx_v0, tWzx0, tWzx0L, DD, 2*LL, DD);
  put(7,  W_zx_v2, tWzx2, tWzx2L, DD, 2*LL, DD);
  put(8,  W_zx_v3, tWzx3, tWzx3L, DD, 2*LL, DD);
  put(9,  W_zy_v4, tWzy,  tWzyL,  DD, 2*PP, DD);
  put(10, W_rot,   tWcat, tWcatL, DD, P2C,  DD);
  put(11, W_koo,   tWcat + (size_t)P2C * DD, tWcatL + (size_t)P2C * DD, DD, 2*PP, DD);
  const int total_tiles = base;

  k_convert<<<dim3(total_tiles), dim3(256), 0, stream>>>(tab);
  k_xpose<<<dim3(45, 4, 64), dim3(16, 16), 0, stream>>>(x_bsd, xhi, xlo);

  const dim3 blk(256);
  // h = gelu(x @ W_h)
  k_gemm<1, false, false, false><<<dim3(8, 64), blk, 0, stream>>>(
      xhi, xlo, LLP, tWh, tWhL, LLP,
      nullptr, nullptr, nullptr, 0, 0.f, nullptr, hhi, hlo, HH, LLP, HH);
  // z = affine(z0*0.1, h, W_ssz)
  k_gemm<0, true, false, false><<<dim3(8, 64), blk, 0, stream>>>(
      hhi, hlo, HH, tWssz, tWsszL, DD,
      z0, nullptr, nullptr, DD, 0.1f, nullptr, zhi, zlo, DD, DD, DD);
  // x = affine(x, z, W_zx_v0)
  k_gemm<0, true, true, false><<<dim3(12, 64), blk, 0, stream>>>(
      zhi, zlo, DD, tWzx0, tWzx0L, DD,
      nullptr, xhi, xlo, LLP, 1.f, nullptr, xhi, xlo, LLP, DD, LL);
  // z = affine(z, x, W_xz_v2)
  k_gemm<0, true, true, false><<<dim3(8, 64), blk, 0, stream>>>(
      xhi, xlo, LLP, tWxz2, tWxz2L, LLP,
      nullptr, zhi, zlo, DD, 1.f, nullptr, zhi, zlo, DD, LLP, DD);
  // x = affine(x, z, W_zx_v2)
  k_gemm<0, true, true, false><<<dim3(12, 64), blk, 0, stream>>>(
      zhi, zlo, DD, tWzx2, tWzx2L, DD,
      nullptr, xhi, xlo, LLP, 1.f, nullptr, xhi, xlo, LLP, DD, LL);
  // z = affine(z, x, W_xz_v3)
  k_gemm<0, true, true, false><<<dim3(8, 64), blk, 0, stream>>>(
      xhi, xlo, LLP, tWxz3, tWxz3L, LLP,
      nullptr, zhi, zlo, DD, 1.f, nullptr, zhi, zlo, DD, LLP, DD);
  // x = affine(x, z, W_zx_v3)
  k_gemm<0, true, true, false><<<dim3(12, 64), blk, 0, stream>>>(
      zhi, zlo, DD, tWzx3, tWzx3L, DD,
      nullptr, xhi, xlo, LLP, 1.f, nullptr, xhi, xlo, LLP, DD, LL);
  // z = affine(z, x, W_xz_v4)
  k_gemm<0, true, true, false><<<dim3(8, 64), blk, 0, stream>>>(
      xhi, xlo, LLP, tWxz4, tWxz4L, LLP,
      nullptr, zhi, zlo, DD, 1.f, nullptr, zhi, zlo, DD, LLP, DD);
  // yT = affine(y0*0.1, z, W_zy_v4)  [transposed fp32 out]
  k_gemm<0, true, false, true><<<dim3(6, 64), blk, 0, stream>>>(
      zhi, zlo, DD, tWzy, tWzyL, DD,
      y0, nullptr, nullptr, PP, 0.1f, yT, nullptr, nullptr, 0, DD, PP);
  // z = affine(z, x, W_xz_v5)
  k_gemm<0, true, true, false><<<dim3(8, 64), blk, 0, stream>>>(
      xhi, xlo, LLP, tWxz5, tWxz5L, LLP,
      nullptr, zhi, zlo, DD, 1.f, nullptr, zhi, zlo, DD, LLP, DD);
  // Pt = z @ [W_rot | W_koo]  (raw, transposed fp32 out): 840 cols
  k_gemm<2, false, false, true><<<dim3(14, 64), blk, 0, stream>>>(
      zhi, zlo, DD, tWcat, tWcatL, DD,
      nullptr, nullptr, nullptr, 0, 0.f, Pt, nullptr, nullptr, 0, DD, P2C * 5);
  // final elementwise + transposed store
  k_final<<<dim3(42, 64), dim3(64, 4), 0, stream>>>(Pt, yT, a_y, b_y, out);
}